// Round 1
// baseline (1203.579 us; speedup 1.0000x reference)
//
#include <hip/hip_runtime.h>
#include <hip/hip_bf16.h>
#include <math.h>

// Problem constants (match reference setup_inputs)
#define NTOK 4096
#define DM   1024
#define NE   16
#define HID  2048
#define NPAIR (NTOK*2)          // exactly top-2 routing -> 8192 (token,expert) pairs

// GEMM tiling
#define BM 64
#define BN 128
#define BK 16
#define MSLOTS (NPAIR/BM + NE)  // 128 + 16 = 144 m-tile slots (covers per-expert ceil waste)

__device__ __forceinline__ float gelu_exact(float v) {
    return 0.5f * v * (1.0f + erff(v * 0.70710678118654752440f));
}

__device__ __forceinline__ void store_h(float* p, float v) { *p = v; }
__device__ __forceinline__ void store_h(__hip_bfloat16* p, float v) { *p = __float2bfloat16(v); }
__device__ __forceinline__ float load_h(const float* p) { return *p; }
__device__ __forceinline__ float load_h(const __hip_bfloat16* p) { return __bfloat162float(*p); }

// ---------------------------------------------------------------------------
// Routing compaction
// ---------------------------------------------------------------------------
__global__ void k_init(float* __restrict__ out, int* __restrict__ cnt, int* __restrict__ cnt2) {
    int i = blockIdx.x * blockDim.x + threadIdx.x;
    if (i < NTOK * DM) out[i] = 0.0f;
    if (i < NE) { cnt[i] = 0; cnt2[i] = 0; }
}

__global__ void k_count(const float* __restrict__ rt, int* __restrict__ cnt) {
    int i = blockIdx.x * blockDim.x + threadIdx.x;   // i = n*NE + e
    if (i >= NTOK * NE) return;
    if (rt[i] > 0.0f) atomicAdd(&cnt[i & (NE - 1)], 1);
}

__global__ void k_scan(const int* __restrict__ cnt, int* __restrict__ offs, int* __restrict__ ts) {
    // single thread: E=16 trivial exclusive scans (pair offsets + m-tile starts)
    int o = 0, t = 0;
    for (int e = 0; e < NE; ++e) {
        offs[e] = o; ts[e] = t;
        o += cnt[e];
        t += (cnt[e] + BM - 1) / BM;
    }
    ts[NE] = t;
}

__global__ void k_fill(const float* __restrict__ rt, const int* __restrict__ offs,
                       int* __restrict__ cnt2, int* __restrict__ ptok, float* __restrict__ pscore) {
    int i = blockIdx.x * blockDim.x + threadIdx.x;   // i = n*NE + e
    if (i >= NTOK * NE) return;
    float s = rt[i];
    if (s > 0.0f) {
        int e = i & (NE - 1);
        int n = i >> 4;
        int slot = atomicAdd(&cnt2[e], 1);
        int pos = offs[e] + slot;
        ptok[pos] = n;
        pscore[pos] = s;
    }
}

// ---------------------------------------------------------------------------
// GEMM1: h[pos, :] = gelu(x[tok[pos], :] @ W0[e] + b0[e])   (per-expert tiles)
// ---------------------------------------------------------------------------
template <typename HT>
__global__ __launch_bounds__(256) void k_gemm1(
    const float* __restrict__ x, const float* __restrict__ W0, const float* __restrict__ b0,
    const int* __restrict__ cnt, const int* __restrict__ offs, const int* __restrict__ ts,
    const int* __restrict__ ptok, HT* __restrict__ h)
{
    __shared__ float As[BK][BM + 4];   // transposed A tile
    __shared__ float Bs[BK][BN + 4];
    __shared__ int   toks[BM];

    int mt = blockIdx.x;
    if (mt >= ts[NE]) return;
    int e = 0;
    while (mt >= ts[e + 1]) ++e;
    int lm = mt - ts[e];
    int mcnt = cnt[e];
    int row0 = offs[e] + lm * BM;
    int rowsValid = min(BM, mcnt - lm * BM);
    int n0 = blockIdx.y * BN;
    int tid = threadIdx.x;

    if (tid < BM) toks[tid] = ptok[row0 + min(tid, rowsValid - 1)];
    __syncthreads();

    const float* W0e = W0 + (size_t)e * DM * HID;
    int rg = tid >> 4;         // 0..15 row group (4 rows each)
    int cg = tid & 15;         // 0..15 col group (4+4 cols, split by 64)

    float acc[4][8];
#pragma unroll
    for (int i = 0; i < 4; ++i)
#pragma unroll
        for (int j = 0; j < 8; ++j) acc[i][j] = 0.0f;

    int arow = tid >> 2;              // 0..63
    int akk  = (tid & 3) * 4;         // 0,4,8,12
    int brow = tid >> 4;              // 0..15
    int bcol = (tid & 15) * 4;        // 0..60

    for (int k0 = 0; k0 < DM; k0 += BK) {
        // stage A (gathered x rows), transposed into LDS
        {
            const float* src = x + (size_t)toks[arow] * DM + k0 + akk;
            float4 v = *(const float4*)src;
            As[akk + 0][arow] = v.x;
            As[akk + 1][arow] = v.y;
            As[akk + 2][arow] = v.z;
            As[akk + 3][arow] = v.w;
        }
        // stage B (W0 rows)
        {
            const float* src = W0e + (size_t)(k0 + brow) * HID + n0 + bcol;
            float4 v0 = *(const float4*)src;
            float4 v1 = *(const float4*)(src + 64);
            *(float4*)&Bs[brow][bcol]      = v0;
            *(float4*)&Bs[brow][bcol + 64] = v1;
        }
        __syncthreads();
#pragma unroll
        for (int k = 0; k < BK; ++k) {
            float4 av  = *(const float4*)&As[k][rg * 4];
            float4 bv0 = *(const float4*)&Bs[k][cg * 4];
            float4 bv1 = *(const float4*)&Bs[k][cg * 4 + 64];
            float a[4] = {av.x, av.y, av.z, av.w};
            float b[8] = {bv0.x, bv0.y, bv0.z, bv0.w, bv1.x, bv1.y, bv1.z, bv1.w};
#pragma unroll
            for (int i = 0; i < 4; ++i)
#pragma unroll
                for (int j = 0; j < 8; ++j) acc[i][j] = fmaf(a[i], b[j], acc[i][j]);
        }
        __syncthreads();
    }

    const float* b0e = b0 + (size_t)e * HID;
#pragma unroll
    for (int i = 0; i < 4; ++i) {
        int r = rg * 4 + i;
        if (r < rowsValid) {
            size_t hbase = (size_t)(row0 + r) * HID;
#pragma unroll
            for (int g = 0; g < 2; ++g) {
                int cb = n0 + g * 64 + cg * 4;
#pragma unroll
                for (int j = 0; j < 4; ++j) {
                    float v = acc[i][g * 4 + j] + b0e[cb + j];
                    store_h(h + hbase + cb + j, gelu_exact(v));
                }
            }
        }
    }
}

// ---------------------------------------------------------------------------
// GEMM2: out[tok[pos], :] += score[pos] * (h[pos, :] @ W1[e] + b1[e])
// ---------------------------------------------------------------------------
template <typename HT>
__global__ __launch_bounds__(256) void k_gemm2(
    const HT* __restrict__ h, const float* __restrict__ W1, const float* __restrict__ b1,
    const int* __restrict__ cnt, const int* __restrict__ offs, const int* __restrict__ ts,
    const int* __restrict__ ptok, const float* __restrict__ pscore,
    float* __restrict__ out)
{
    __shared__ float As[BK][BM + 4];
    __shared__ float Bs[BK][BN + 4];
    __shared__ int   toks[BM];
    __shared__ float scs[BM];

    int mt = blockIdx.x;
    if (mt >= ts[NE]) return;
    int e = 0;
    while (mt >= ts[e + 1]) ++e;
    int lm = mt - ts[e];
    int mcnt = cnt[e];
    int row0 = offs[e] + lm * BM;
    int rowsValid = min(BM, mcnt - lm * BM);
    int n0 = blockIdx.y * BN;
    int tid = threadIdx.x;

    if (tid < BM) {
        int r = min(tid, rowsValid - 1);
        toks[tid] = ptok[row0 + r];
        scs[tid]  = pscore[row0 + r];
    }
    __syncthreads();

    const float* W1e = W1 + (size_t)e * HID * DM;
    int rg = tid >> 4;
    int cg = tid & 15;

    float acc[4][8];
#pragma unroll
    for (int i = 0; i < 4; ++i)
#pragma unroll
        for (int j = 0; j < 8; ++j) acc[i][j] = 0.0f;

    int arow = tid >> 2;
    int akk  = (tid & 3) * 4;
    int brow = tid >> 4;
    int bcol = (tid & 15) * 4;
    int arowc = min(arow, rowsValid - 1);   // clamp so invalid rows still load valid memory

    for (int k0 = 0; k0 < HID; k0 += BK) {
        {
            const HT* src = h + (size_t)(row0 + arowc) * HID + k0 + akk;
            As[akk + 0][arow] = load_h(src + 0);
            As[akk + 1][arow] = load_h(src + 1);
            As[akk + 2][arow] = load_h(src + 2);
            As[akk + 3][arow] = load_h(src + 3);
        }
        {
            const float* src = W1e + (size_t)(k0 + brow) * DM + n0 + bcol;
            float4 v0 = *(const float4*)src;
            float4 v1 = *(const float4*)(src + 64);
            *(float4*)&Bs[brow][bcol]      = v0;
            *(float4*)&Bs[brow][bcol + 64] = v1;
        }
        __syncthreads();
#pragma unroll
        for (int k = 0; k < BK; ++k) {
            float4 av  = *(const float4*)&As[k][rg * 4];
            float4 bv0 = *(const float4*)&Bs[k][cg * 4];
            float4 bv1 = *(const float4*)&Bs[k][cg * 4 + 64];
            float a[4] = {av.x, av.y, av.z, av.w};
            float b[8] = {bv0.x, bv0.y, bv0.z, bv0.w, bv1.x, bv1.y, bv1.z, bv1.w};
#pragma unroll
            for (int i = 0; i < 4; ++i)
#pragma unroll
                for (int j = 0; j < 8; ++j) acc[i][j] = fmaf(a[i], b[j], acc[i][j]);
        }
        __syncthreads();
    }

    const float* b1e = b1 + (size_t)e * DM;
#pragma unroll
    for (int i = 0; i < 4; ++i) {
        int r = rg * 4 + i;
        if (r < rowsValid) {
            int t = toks[r];
            float sc = scs[r];
            size_t obase = (size_t)t * DM;
#pragma unroll
            for (int g = 0; g < 2; ++g) {
                int cb = n0 + g * 64 + cg * 4;
#pragma unroll
                for (int j = 0; j < 4; ++j) {
                    float v = acc[i][g * 4 + j] + b1e[cb + j];
                    atomicAdd(out + obase + cb + j, sc * v);
                }
            }
        }
    }
}

// ---------------------------------------------------------------------------
// Launch
// ---------------------------------------------------------------------------
extern "C" void kernel_launch(void* const* d_in, const int* in_sizes, int n_in,
                              void* d_out, int out_size, void* d_ws, size_t ws_size,
                              hipStream_t stream) {
    const float* x  = (const float*)d_in[0];
    const float* rt = (const float*)d_in[1];
    const float* W0 = (const float*)d_in[2];
    const float* b0 = (const float*)d_in[3];
    const float* W1 = (const float*)d_in[4];
    const float* b1 = (const float*)d_in[5];
    float* out = (float*)d_out;

    char* ws = (char*)d_ws;
    int* cnt  = (int*)ws;          // [16]
    int* cnt2 = cnt + 16;          // [16]
    int* offs = cnt + 32;          // [16]
    int* ts   = cnt + 48;          // [17]
    int*   ptok   = (int*)(ws + 512);                    // [NPAIR]
    float* pscore = (float*)(ws + 512 + NPAIR * 4);      // [NPAIR]
    void*  hbuf   = (void*)(ws + (1u << 20));            // h buffer

    k_init<<<(NTOK * DM + 255) / 256, 256, 0, stream>>>(out, cnt, cnt2);
    k_count<<<(NTOK * NE) / 256, 256, 0, stream>>>(rt, cnt);
    k_scan<<<1, 1, 0, stream>>>(cnt, offs, ts);
    k_fill<<<(NTOK * NE) / 256, 256, 0, stream>>>(rt, offs, cnt2, ptok, pscore);

    size_t need_f32 = (size_t)(1u << 20) + (size_t)NPAIR * HID * 4;
    if (ws_size >= need_f32) {
        float* h = (float*)hbuf;
        k_gemm1<float><<<dim3(MSLOTS, HID / BN), 256, 0, stream>>>(x, W0, b0, cnt, offs, ts, ptok, h);
        k_gemm2<float><<<dim3(MSLOTS, DM / BN), 256, 0, stream>>>(h, W1, b1, cnt, offs, ts, ptok, pscore, out);
    } else {
        // ws too small for fp32 h: fall back to bf16 h (32 MB)
        __hip_bfloat16* h = (__hip_bfloat16*)hbuf;
        k_gemm1<__hip_bfloat16><<<dim3(MSLOTS, HID / BN), 256, 0, stream>>>(x, W0, b0, cnt, offs, ts, ptok, h);
        k_gemm2<__hip_bfloat16><<<dim3(MSLOTS, DM / BN), 256, 0, stream>>>(h, W1, b1, cnt, offs, ts, ptok, pscore, out);
    }
}

// Round 2
// 662.949 us; speedup vs baseline: 1.8155x; 1.8155x over previous
//
#include <hip/hip_runtime.h>
#include <hip/hip_bf16.h>
#include <math.h>

// Problem constants
#define NTOK 4096
#define DM   1024
#define NE   16
#define HID  2048
#define NPAIR (NTOK*2)

// GEMM tiling (both GEMMs): block 256x128, BK=32, 256 threads = 4 waves,
// wave tile 128x64 (8x4 fragments of 16x16), LDS rows padded to 40 shorts.
#define BM 256
#define BN 128
#define BK 32
#define LDT 40          // LDS row stride in shorts (32 data + 8 pad; 80B, 16B-aligned)
#define MSLOTS (NPAIR/BM + NE)   // 32 + 16 = 48

typedef __attribute__((ext_vector_type(4))) float f32x4;
typedef __attribute__((ext_vector_type(8))) short bf16x8;

__device__ __forceinline__ float gelu_exact(float v) {
    return 0.5f * v * (1.0f + erff(v * 0.70710678118654752440f));
}
__device__ __forceinline__ short f2bf(float f) {
    __hip_bfloat16 b = __float2bfloat16(f);
    return __builtin_bit_cast(short, b);
}

// ---------------------------------------------------------------------------
// Routing compaction
// ---------------------------------------------------------------------------
__global__ void k_init(float* __restrict__ out, int* __restrict__ cnt, int* __restrict__ cnt2) {
    int i = blockIdx.x * blockDim.x + threadIdx.x;
    if (i < NTOK * DM / 4) ((float4*)out)[i] = make_float4(0.f, 0.f, 0.f, 0.f);
    if (i < NE) { cnt[i] = 0; cnt2[i] = 0; }
}

__global__ void k_count(const float* __restrict__ rt, int* __restrict__ cnt) {
    int i = blockIdx.x * blockDim.x + threadIdx.x;
    if (i >= NTOK * NE) return;
    if (rt[i] > 0.0f) atomicAdd(&cnt[i & (NE - 1)], 1);
}

__global__ void k_scan(const int* __restrict__ cnt, int* __restrict__ offs, int* __restrict__ ts) {
    int o = 0, t = 0;
    for (int e = 0; e < NE; ++e) {
        offs[e] = o; ts[e] = t;
        o += cnt[e];
        t += (cnt[e] + BM - 1) / BM;
    }
    ts[NE] = t;
}

__global__ void k_fill(const float* __restrict__ rt, const int* __restrict__ offs,
                       int* __restrict__ cnt2, int* __restrict__ ptok, float* __restrict__ pscore) {
    int i = blockIdx.x * blockDim.x + threadIdx.x;
    if (i >= NTOK * NE) return;
    float s = rt[i];
    if (s > 0.0f) {
        int e = i & (NE - 1);
        int n = i >> 4;
        int slot = atomicAdd(&cnt2[e], 1);
        int pos = offs[e] + slot;
        ptok[pos] = n;
        pscore[pos] = s;
    }
}

// ---------------------------------------------------------------------------
// GEMM1 (MFMA): h[pos,:] = gelu(x[tok[pos],:] @ W0[e] + b0[e]), bf16 out
// ---------------------------------------------------------------------------
__global__ __launch_bounds__(256, 2) void k_gemm1(
    const float* __restrict__ x, const float* __restrict__ W0, const float* __restrict__ b0,
    const int* __restrict__ cnt, const int* __restrict__ offs, const int* __restrict__ ts,
    const int* __restrict__ ptok, short* __restrict__ h)
{
    __shared__ short As[BM * LDT];
    __shared__ short Bs[BN * LDT];
    __shared__ int toks_s[BM];

    int mt = blockIdx.x;
    if (mt >= ts[NE]) return;
    int e = 0;
    while (mt >= ts[e + 1]) ++e;
    int lm = mt - ts[e];
    int row0 = offs[e] + lm * BM;
    int rowsValid = min(BM, cnt[e] - lm * BM);
    int n0 = blockIdx.y * BN;
    int tid = threadIdx.x;

    toks_s[tid] = ptok[row0 + min(tid, rowsValid - 1)];
    __syncthreads();

    const float* W0e = W0 + (size_t)e * DM * HID;
    int lane = tid & 63, wid = tid >> 6;
    int wm = wid >> 1, wn = wid & 1;           // wave tile: rows wm*128, cols wn*64
    int fr = lane & 15, fg = lane >> 4;

    // B staging: thread -> (bn, k-octet bkq); loads cols n0+bn and n0+bn+64
    int bn = tid & 63, bkq = tid >> 6;         // bkq 0..3 -> k = bkq*8 .. +7
    const float* bbase = W0e + (size_t)(bkq * 8) * HID + n0 + bn;
    // A staging: one thread per row
    int am = tid;
    const float* aptr = x + (size_t)toks_s[am] * DM;

    f32x4 acc[8][4];
#pragma unroll
    for (int i = 0; i < 8; ++i)
#pragma unroll
        for (int j = 0; j < 4; ++j) acc[i][j] = (f32x4)0.0f;

    float br0[16], br1[16];
#pragma unroll
    for (int kk = 0; kk < 8; ++kk) {
        br0[kk]     = bbase[(size_t)kk * HID];
        br0[kk + 8] = bbase[(size_t)kk * HID + 64];
    }

    auto STEP = [&](float (&brC)[16], float (&brN)[16], int kt) {
        // issue A loads early (latency hides under B cvt+write)
        float4 ar[8];
#pragma unroll
        for (int j = 0; j < 8; ++j) ar[j] = *(const float4*)(aptr + kt + j * 4);
        // write B tile (transposed, cvt to bf16)
        bf16x8 p0, p1;
#pragma unroll
        for (int kk = 0; kk < 8; ++kk) { p0[kk] = f2bf(brC[kk]); p1[kk] = f2bf(brC[kk + 8]); }
        *(bf16x8*)&Bs[bn * LDT + bkq * 8]        = p0;
        *(bf16x8*)&Bs[(bn + 64) * LDT + bkq * 8] = p1;
        // write A tile
        float av[32];
#pragma unroll
        for (int j = 0; j < 8; ++j) {
            av[4 * j + 0] = ar[j].x; av[4 * j + 1] = ar[j].y;
            av[4 * j + 2] = ar[j].z; av[4 * j + 3] = ar[j].w;
        }
#pragma unroll
        for (int c = 0; c < 4; ++c) {
            bf16x8 pa;
#pragma unroll
            for (int u = 0; u < 8; ++u) pa[u] = f2bf(av[c * 8 + u]);
            *(bf16x8*)&As[am * LDT + c * 8] = pa;
        }
        __syncthreads();
        // prefetch next B panel
        if (kt + BK < DM) {
            const float* bp = bbase + (size_t)(kt + BK) * HID;
#pragma unroll
            for (int kk = 0; kk < 8; ++kk) {
                brN[kk]     = bp[(size_t)kk * HID];
                brN[kk + 8] = bp[(size_t)kk * HID + 64];
            }
        }
        // compute: 8x4 fragments
        bf16x8 bfr[4];
#pragma unroll
        for (int j = 0; j < 4; ++j)
            bfr[j] = *(bf16x8*)&Bs[(wn * 64 + j * 16 + fr) * LDT + fg * 8];
#pragma unroll
        for (int i = 0; i < 8; ++i) {
            bf16x8 af = *(bf16x8*)&As[(wm * 128 + i * 16 + fr) * LDT + fg * 8];
#pragma unroll
            for (int j = 0; j < 4; ++j)
                acc[i][j] = __builtin_amdgcn_mfma_f32_16x16x32_bf16(af, bfr[j], acc[i][j], 0, 0, 0);
        }
        __syncthreads();
    };

    for (int kt = 0; kt < DM; kt += 2 * BK) {
        STEP(br0, br1, kt);
        STEP(br1, br0, kt + BK);
    }

    // epilogue: bias + gelu -> bf16 h
    const float* b0e = b0 + (size_t)e * HID + n0 + wn * 64;
    float bias[4];
#pragma unroll
    for (int j = 0; j < 4; ++j) bias[j] = b0e[j * 16 + fr];
#pragma unroll
    for (int i = 0; i < 8; ++i)
#pragma unroll
        for (int r = 0; r < 4; ++r) {
            int m = wm * 128 + i * 16 + fg * 4 + r;
            if (m < rowsValid) {
                short* hrow = h + (size_t)(row0 + m) * HID + n0 + wn * 64;
#pragma unroll
                for (int j = 0; j < 4; ++j)
                    hrow[j * 16 + fr] = f2bf(gelu_exact(acc[i][j][r] + bias[j]));
            }
        }
}

// ---------------------------------------------------------------------------
// GEMM2 (MFMA): out[tok[pos],:] += score * (h[pos,:] @ W1[e] + b1[e])
// ---------------------------------------------------------------------------
__global__ __launch_bounds__(256, 2) void k_gemm2(
    const short* __restrict__ h, const float* __restrict__ W1, const float* __restrict__ b1,
    const int* __restrict__ cnt, const int* __restrict__ offs, const int* __restrict__ ts,
    const int* __restrict__ ptok, const float* __restrict__ pscore,
    float* __restrict__ out)
{
    __shared__ short As[BM * LDT];
    __shared__ short Bs[BN * LDT];
    __shared__ int toks_s[BM];
    __shared__ float scs_s[BM];

    int mt = blockIdx.x;
    if (mt >= ts[NE]) return;
    int e = 0;
    while (mt >= ts[e + 1]) ++e;
    int lm = mt - ts[e];
    int row0 = offs[e] + lm * BM;
    int rowsValid = min(BM, cnt[e] - lm * BM);
    int n0 = blockIdx.y * BN;
    int tid = threadIdx.x;

    {
        int r = min(tid, rowsValid - 1);
        toks_s[tid] = ptok[row0 + r];
        scs_s[tid]  = pscore[row0 + r];
    }
    __syncthreads();

    const float* W1e = W1 + (size_t)e * HID * DM;
    int lane = tid & 63, wid = tid >> 6;
    int wm = wid >> 1, wn = wid & 1;
    int fr = lane & 15, fg = lane >> 4;

    int bn = tid & 63, bkq = tid >> 6;
    const float* bbase = W1e + (size_t)(bkq * 8) * DM + n0 + bn;
    int am = tid;
    const short* aptr = h + (size_t)(row0 + min(am, rowsValid - 1)) * HID;

    f32x4 acc[8][4];
#pragma unroll
    for (int i = 0; i < 8; ++i)
#pragma unroll
        for (int j = 0; j < 4; ++j) acc[i][j] = (f32x4)0.0f;

    float br0[16], br1[16];
#pragma unroll
    for (int kk = 0; kk < 8; ++kk) {
        br0[kk]     = bbase[(size_t)kk * DM];
        br0[kk + 8] = bbase[(size_t)kk * DM + 64];
    }

    auto STEP = [&](float (&brC)[16], float (&brN)[16], int kt) {
        // A: bf16 h rows, direct 16B loads, no conversion
        bf16x8 ha[4];
#pragma unroll
        for (int c = 0; c < 4; ++c) ha[c] = *(const bf16x8*)(aptr + kt + c * 8);
        // write B (cvt)
        bf16x8 p0, p1;
#pragma unroll
        for (int kk = 0; kk < 8; ++kk) { p0[kk] = f2bf(brC[kk]); p1[kk] = f2bf(brC[kk + 8]); }
        *(bf16x8*)&Bs[bn * LDT + bkq * 8]        = p0;
        *(bf16x8*)&Bs[(bn + 64) * LDT + bkq * 8] = p1;
        // write A
#pragma unroll
        for (int c = 0; c < 4; ++c) *(bf16x8*)&As[am * LDT + c * 8] = ha[c];
        __syncthreads();
        if (kt + BK < HID) {
            const float* bp = bbase + (size_t)(kt + BK) * DM;
#pragma unroll
            for (int kk = 0; kk < 8; ++kk) {
                brN[kk]     = bp[(size_t)kk * DM];
                brN[kk + 8] = bp[(size_t)kk * DM + 64];
            }
        }
        bf16x8 bfr[4];
#pragma unroll
        for (int j = 0; j < 4; ++j)
            bfr[j] = *(bf16x8*)&Bs[(wn * 64 + j * 16 + fr) * LDT + fg * 8];
#pragma unroll
        for (int i = 0; i < 8; ++i) {
            bf16x8 af = *(bf16x8*)&As[(wm * 128 + i * 16 + fr) * LDT + fg * 8];
#pragma unroll
            for (int j = 0; j < 4; ++j)
                acc[i][j] = __builtin_amdgcn_mfma_f32_16x16x32_bf16(af, bfr[j], acc[i][j], 0, 0, 0);
        }
        __syncthreads();
    };

    for (int kt = 0; kt < HID; kt += 2 * BK) {
        STEP(br0, br1, kt);
        STEP(br1, br0, kt + BK);
    }

    const float* b1e = b1 + (size_t)e * DM + n0 + wn * 64;
    float bias[4];
#pragma unroll
    for (int j = 0; j < 4; ++j) bias[j] = b1e[j * 16 + fr];
#pragma unroll
    for (int i = 0; i < 8; ++i)
#pragma unroll
        for (int r = 0; r < 4; ++r) {
            int m = wm * 128 + i * 16 + fg * 4 + r;
            if (m < rowsValid) {
                float sc = scs_s[m];
                float* orow = out + (size_t)toks_s[m] * DM + n0 + wn * 64;
#pragma unroll
                for (int j = 0; j < 4; ++j)
                    atomicAdd(&orow[j * 16 + fr], sc * (acc[i][j][r] + bias[j]));
            }
        }
}

// ---------------------------------------------------------------------------
// Launch
// ---------------------------------------------------------------------------
extern "C" void kernel_launch(void* const* d_in, const int* in_sizes, int n_in,
                              void* d_out, int out_size, void* d_ws, size_t ws_size,
                              hipStream_t stream) {
    const float* x  = (const float*)d_in[0];
    const float* rt = (const float*)d_in[1];
    const float* W0 = (const float*)d_in[2];
    const float* b0 = (const float*)d_in[3];
    const float* W1 = (const float*)d_in[4];
    const float* b1 = (const float*)d_in[5];
    float* out = (float*)d_out;

    char* ws = (char*)d_ws;
    int* cnt  = (int*)ws;
    int* cnt2 = cnt + 16;
    int* offs = cnt + 32;
    int* ts   = cnt + 48;
    int*   ptok   = (int*)(ws + 512);
    float* pscore = (float*)(ws + 512 + NPAIR * 4);
    short* hbuf   = (short*)(ws + (1u << 20));   // bf16 h, NPAIR x HID = 33.5 MB

    k_init<<<(NTOK * DM / 4 + 255) / 256, 256, 0, stream>>>(out, cnt, cnt2);
    k_count<<<(NTOK * NE) / 256, 256, 0, stream>>>(rt, cnt);
    k_scan<<<1, 1, 0, stream>>>(cnt, offs, ts);
    k_fill<<<(NTOK * NE) / 256, 256, 0, stream>>>(rt, offs, cnt2, ptok, pscore);

    k_gemm1<<<dim3(MSLOTS, HID / BN), 256, 0, stream>>>(x, W0, b0, cnt, offs, ts, ptok, hbuf);
    k_gemm2<<<dim3(MSLOTS, DM / BN), 256, 0, stream>>>(hbuf, W1, b1, cnt, offs, ts, ptok, pscore, out);
}